// Round 5
// baseline (58.942 us; speedup 1.0000x reference)
//
#include <hip/hip_runtime.h>
#include <hip/hip_bf16.h>
#include <stdint.h>

// ---------------------------------------------------------------------------
// GraphicalBranch: out[r] = relu(x[row_r] @ W_self + (S_{b_r} @ W_nbr) + bias)
//   S_b = sum of the 28 pair-node rows of sample b
//   row_r = b*28 + pidx(pmin,pmax), pidx = 7i - i(i-1)/2 + (j-i-1)  [analytic]
// K1 prep (1536 blks): S-sum + fused gather->Abf | W^T -> bf16
// K2 fused GEMM (128x4 blks): BARRIER-FREE register GEMM. All operands are
//   L2/L3-resident (W 1MB, Abf 10MB), so no LDS staging: each wave loads its
//   MFMA fragments straight from global (dwordx4), 1-deep named-reg prefetch,
//   no __syncthreads in the K-loop. Strips 0..4 = 80 rel rows (@Wself^T),
//   strip 5 = 8 S rows dup-padded (@Wnbr^T -> T). T exchanged intra-wave via
//   per-wave LDS + one trailing barrier. Epilogue: relu(acc + T[sample] + b).
// ---------------------------------------------------------------------------

typedef __bf16 bf16_t;
typedef __bf16 bf16x8 __attribute__((ext_vector_type(8)));
typedef __bf16 bf16x2 __attribute__((ext_vector_type(2)));
typedef float  f32x4  __attribute__((ext_vector_type(4)));

#define D_DIM 512
#define NC2   28
#define NOBJ  8
#define MAXREL 10
#define B_SAMP 1024
#define OUTROWS (B_SAMP * MAXREL)

// --- K1: fused prep --------------------------------------------------------
__global__ __launch_bounds__(256) void prep_kernel(
    const float* __restrict__ x, const float* __restrict__ Wself,
    const float* __restrict__ Wnbr, const int* __restrict__ pairs,
    bf16_t* __restrict__ Sbf, bf16_t* __restrict__ Abf,
    bf16_t* __restrict__ Wst, bf16_t* __restrict__ Wnt)
{
  const int blk = blockIdx.x, tid = threadIdx.x;
  if (blk < B_SAMP) {
    __shared__ int rel_row[MAXREL];
    if (tid < MAXREL) {
      int p0 = pairs[blk * MAXREL * 2 + tid * 2 + 0];
      int p1 = pairs[blk * MAXREL * 2 + tid * 2 + 1];
      int pmin = min(p0, p1), pmax = max(p0, p1);
      rel_row[tid] = 7 * pmin - (pmin * (pmin - 1)) / 2 + (pmax - pmin - 1);
    }
    __syncthreads();
    int rr[MAXREL];
    #pragma unroll
    for (int j = 0; j < MAXREL; ++j) rr[j] = rel_row[j];

    const float2* xr = (const float2*)(x + (size_t)blk * NC2 * D_DIM);
    float2 a = {0.f, 0.f};
    #pragma unroll
    for (int r = 0; r < NC2; ++r) {
      float2 v = xr[r * (D_DIM / 2) + tid];
      a.x += v.x; a.y += v.y;
      bf16x2 o = { (bf16_t)v.x, (bf16_t)v.y };
      #pragma unroll
      for (int j = 0; j < MAXREL; ++j)
        if (rr[j] == r)   // block-uniform -> scalar branch
          *(bf16x2*)(Abf + (size_t)(blk * MAXREL + j) * D_DIM + tid * 2) = o;
    }
    bf16x2 o = { (bf16_t)a.x, (bf16_t)a.y };
    *(bf16x2*)(Sbf + (size_t)blk * D_DIM + tid * 2) = o;
  } else {
    __shared__ float tile[32][33];
    const int t = blk - B_SAMP;
    const float* W  = (t & 256) ? Wnbr : Wself;
    bf16_t*     Wt  = (t & 256) ? Wnt  : Wst;
    const int r = t & 255;
    const int k0 = (r & 15) * 32, n0 = (r >> 4) * 32;
    const int tx = tid & 31, ty = tid >> 5;
    #pragma unroll
    for (int i = 0; i < 32; i += 8)
      tile[ty + i][tx] = W[(size_t)(k0 + ty + i) * D_DIM + n0 + tx];
    __syncthreads();
    #pragma unroll
    for (int i = 0; i < 32; i += 8)
      Wt[(size_t)(n0 + ty + i) * D_DIM + k0 + tx] = (bf16_t)tile[tx][ty + i];
  }
}

// --- K2: barrier-free register GEMM ----------------------------------------
// Block (bx, by): 8 samples, out rows [bx*80, +80), cols [by*128, +128).
// Wave w owns cols [by*128 + w*32, +32). Frag loads straight from global.
#define LOADF(A, B, k) do {                                                   \
    _Pragma("unroll")                                                         \
    for (int s_ = 0; s_ < 6; ++s_)                                            \
      A[s_] = *(const bf16x8*)(pA[s_] + (k) * 32);                            \
    B[0] = *(const bf16x8*)(pB0 + (k) * 32);                                  \
    B[1] = *(const bf16x8*)(pB1 + (k) * 32);                                  \
    B[2] = *(const bf16x8*)(pN0 + (k) * 32);                                  \
    B[3] = *(const bf16x8*)(pN1 + (k) * 32);                                  \
  } while (0)

#define DOMFMA(A, B) do {                                                     \
    _Pragma("unroll")                                                         \
    for (int s_ = 0; s_ < 5; ++s_) {                                          \
      acc[s_][0] = __builtin_amdgcn_mfma_f32_16x16x32_bf16(A[s_], B[0], acc[s_][0], 0, 0, 0); \
      acc[s_][1] = __builtin_amdgcn_mfma_f32_16x16x32_bf16(A[s_], B[1], acc[s_][1], 0, 0, 0); \
    }                                                                         \
    acc[5][0] = __builtin_amdgcn_mfma_f32_16x16x32_bf16(A[5], B[2], acc[5][0], 0, 0, 0); \
    acc[5][1] = __builtin_amdgcn_mfma_f32_16x16x32_bf16(A[5], B[3], acc[5][1], 0, 0, 0); \
  } while (0)

__global__ __launch_bounds__(256) void fused_gemm_kernel(
    const bf16_t* __restrict__ Abf, const bf16_t* __restrict__ Sbf,
    const bf16_t* __restrict__ Wst, const bf16_t* __restrict__ Wnt,
    const float* __restrict__ bias, float* __restrict__ out)
{
  __shared__ float Tex[4][16][33];   // per-wave T exchange (intra-wave only)

  const int tid = threadIdx.x;
  const int w = tid >> 6, l = tid & 63;
  const int kg = l >> 4, lr = l & 15;
  const int n0 = blockIdx.y * 128 + w * 32;   // wave's col base
  const int arow0 = blockIdx.x * 80;
  const int srow0 = blockIdx.x * 8;

  // fragment stream base pointers (k advances via immediate offsets)
  const bf16_t* pA[6];
  #pragma unroll
  for (int s = 0; s < 5; ++s)
    pA[s] = Abf + (size_t)(arow0 + s * 16 + lr) * D_DIM + kg * 8;
  pA[5] = Sbf + (size_t)(srow0 + (lr & 7)) * D_DIM + kg * 8;
  const bf16_t* pB0 = Wst + (size_t)(n0 + lr) * D_DIM + kg * 8;
  const bf16_t* pB1 = Wst + (size_t)(n0 + 16 + lr) * D_DIM + kg * 8;
  const bf16_t* pN0 = Wnt + (size_t)(n0 + lr) * D_DIM + kg * 8;
  const bf16_t* pN1 = Wnt + (size_t)(n0 + 16 + lr) * D_DIM + kg * 8;

  f32x4 acc[6][2] = {};
  bf16x8 aX[6], bX[4], aY[6], bY[4];

  LOADF(aX, bX, 0);
  #pragma unroll
  for (int t = 0; t < 16; t += 2) {
    if (t + 1 < 16) LOADF(aY, bY, t + 1);
    DOMFMA(aX, bX);
    if (t + 2 < 16) LOADF(aX, bX, t + 2);
    DOMFMA(aY, bY);
  }

  // T tile -> per-wave LDS.  C/D layout: col = l&15, row = (l>>4)*4 + reg.
  #pragma unroll
  for (int u = 0; u < 2; ++u)
    #pragma unroll
    for (int reg = 0; reg < 4; ++reg)
      Tex[w][kg * 4 + reg][u * 16 + lr] = acc[5][u][reg];
  __syncthreads();

  const float bv0 = bias[n0 + lr];
  const float bv1 = bias[n0 + 16 + lr];
  #pragma unroll
  for (int s = 0; s < 5; ++s) {
    #pragma unroll
    for (int u = 0; u < 2; ++u) {
      #pragma unroll
      for (int reg = 0; reg < 4; ++reg) {
        int rloc = s * 16 + kg * 4 + reg;        // 0..79
        int ls = rloc / MAXREL;                  // local sample 0..7
        int c = u * 16 + lr;
        float v = acc[s][u][reg] + Tex[w][ls][c] + (u ? bv1 : bv0);
        out[(size_t)(arow0 + rloc) * D_DIM + n0 + c] = fmaxf(v, 0.0f);
      }
    }
  }
}

extern "C" void kernel_launch(void* const* d_in, const int* in_sizes, int n_in,
                              void* d_out, int out_size, void* d_ws, size_t ws_size,
                              hipStream_t stream) {
  const float* x     = (const float*)d_in[0];   // [28672, 512]
  const float* Wself = (const float*)d_in[1];   // [512, 512]
  const float* Wnbr  = (const float*)d_in[2];   // [512, 512]
  const float* bias  = (const float*)d_in[3];   // [512]
  const int*   pairs = (const int*)d_in[5];     // [1024, 10, 2]

  char* ws = (char*)d_ws;
  size_t off = 0;
  bf16_t* Sbf = (bf16_t*)(ws + off); off += (size_t)B_SAMP * D_DIM * 2;
  bf16_t* Wst = (bf16_t*)(ws + off); off += (size_t)D_DIM * D_DIM * 2;
  bf16_t* Wnt = (bf16_t*)(ws + off); off += (size_t)D_DIM * D_DIM * 2;
  bf16_t* Abf = (bf16_t*)(ws + off); off += (size_t)OUTROWS * D_DIM * 2;

  prep_kernel<<<B_SAMP + 512, 256, 0, stream>>>(
      x, Wself, Wnbr, pairs, Sbf, Abf, Wst, Wnt);
  fused_gemm_kernel<<<dim3(OUTROWS / 80, D_DIM / 128), 256, 0, stream>>>(
      Abf, Sbf, Wst, Wnt, bias, (float*)d_out);
}

// Round 6
// 35.075 us; speedup vs baseline: 1.6805x; 1.6805x over previous
//
#include <hip/hip_runtime.h>
#include <hip/hip_bf16.h>
#include <stdint.h>

// ---------------------------------------------------------------------------
// GraphicalBranch: out[r] = relu(x[row_r] @ W_self + (S_{b_r} @ W_nbr) + bias)
//   S_b = sum of the 28 pair-node rows of sample b
//   row_r = b*28 + pidx(pmin,pmax), pidx = 7i - i(i-1)/2 + (j-i-1)  [analytic]
// K1 prep (1536 blks): S-sum + fused gather->Abf (float4 loads) | W^T -> bf16
// K2 fused GEMM (128x8 blks, 64-col tiles, 28KB LDS -> 4 blocks/CU):
//   5 strips rel-rows (@Wself^T) + 1 strip S-rows (@Wnbr^T -> T), 2-phase
//   dbuf global_load_lds staging, XOR-swizzled LDS, fused relu/bias/T epilogue
// ---------------------------------------------------------------------------

typedef __bf16 bf16_t;
typedef __bf16 bf16x8 __attribute__((ext_vector_type(8)));
typedef __bf16 bf16x4 __attribute__((ext_vector_type(4)));
typedef float  f32x4  __attribute__((ext_vector_type(4)));

#define D_DIM 512
#define NC2   28
#define NOBJ  8
#define MAXREL 10
#define B_SAMP 1024
#define OUTROWS (B_SAMP * MAXREL)

__device__ __forceinline__ void gload_lds16(const void* g, void* l) {
  __builtin_amdgcn_global_load_lds(
      (const __attribute__((address_space(1))) unsigned int*)g,
      (__attribute__((address_space(3))) unsigned int*)l, 16, 0, 0);
}

// --- K1: fused prep --------------------------------------------------------
// blocks [0,1024):     S[b] = sum of 28 rows -> bf16 (float4, 2-row split);
//                      emit the 10 selected rows as bf16 into Abf while summing
// blocks [1024,1536):  W transpose+convert (256 blocks per matrix)
__global__ __launch_bounds__(256) void prep_kernel(
    const float* __restrict__ x, const float* __restrict__ Wself,
    const float* __restrict__ Wnbr, const int* __restrict__ pairs,
    bf16_t* __restrict__ Sbf, bf16_t* __restrict__ Abf,
    bf16_t* __restrict__ Wst, bf16_t* __restrict__ Wnt)
{
  const int blk = blockIdx.x, tid = threadIdx.x;
  if (blk < B_SAMP) {
    __shared__ int rel_row[MAXREL];
    __shared__ float4 oddsum[128];
    if (tid < MAXREL) {
      int p0 = pairs[blk * MAXREL * 2 + tid * 2 + 0];
      int p1 = pairs[blk * MAXREL * 2 + tid * 2 + 1];
      int pmin = min(p0, p1), pmax = max(p0, p1);
      rel_row[tid] = 7 * pmin - (pmin * (pmin - 1)) / 2 + (pmax - pmin - 1);
    }
    __syncthreads();
    int rr[MAXREL];
    #pragma unroll
    for (int j = 0; j < MAXREL; ++j) rr[j] = rel_row[j];

    const int h = tid >> 7, c = tid & 127;        // half, float4-col
    const float4* x4 = (const float4*)(x + (size_t)blk * NC2 * D_DIM);
    float4 a = {0.f, 0.f, 0.f, 0.f};
    #pragma unroll
    for (int rp = 0; rp < NC2 / 2; ++rp) {
      int r = rp * 2 + h;
      float4 v = x4[r * 128 + c];
      a.x += v.x; a.y += v.y; a.z += v.z; a.w += v.w;
      bf16x4 o = { (bf16_t)v.x, (bf16_t)v.y, (bf16_t)v.z, (bf16_t)v.w };
      #pragma unroll
      for (int j = 0; j < MAXREL; ++j)
        if (rr[j] == r)   // half-uniform predicate
          *(bf16x4*)(Abf + (size_t)(blk * MAXREL + j) * D_DIM + c * 4) = o;
    }
    if (h) oddsum[c] = a;
    __syncthreads();
    if (!h) {
      float4 b = oddsum[c];
      bf16x4 o = { (bf16_t)(a.x + b.x), (bf16_t)(a.y + b.y),
                   (bf16_t)(a.z + b.z), (bf16_t)(a.w + b.w) };
      *(bf16x4*)(Sbf + (size_t)blk * D_DIM + c * 4) = o;
    }
  } else {
    __shared__ float tile[32][33];
    const int t = blk - B_SAMP;
    const float* W  = (t & 256) ? Wnbr : Wself;
    bf16_t*     Wt  = (t & 256) ? Wnt  : Wst;
    const int r = t & 255;
    const int k0 = (r & 15) * 32, n0 = (r >> 4) * 32;
    const int tx = tid & 31, ty = tid >> 5;
    #pragma unroll
    for (int i = 0; i < 32; i += 8)
      tile[ty + i][tx] = W[(size_t)(k0 + ty + i) * D_DIM + n0 + tx];
    __syncthreads();
    #pragma unroll
    for (int i = 0; i < 32; i += 8)
      Wt[(size_t)(n0 + ty + i) * D_DIM + k0 + tx] = (bf16_t)tile[tx][ty + i];
  }
}

// --- K2: fused main GEMM, 64-col tiles, 2-phase dbuf, XOR-swizzled LDS -----
// Block (bx, by): 8 samples, out rows [bx*80, +80), cols [by*64, +64).
// A strips 0..4 = 80 rel rows (@Wst); strip 5 = 8 S rows dup-padded (@Wnt).
// Wave w owns cols [by*64 + w*16, +16).
// LDS chunks (16B): LDS[row][c] = G[row][c ^ ((row>>1)&3)]  (involution).
#define SA_BYTES 6144              // 96 rows * 64 B
#define SB_BYTES 8192              // 2 mats * 64 rows * 64 B
__global__ __launch_bounds__(256) void fused_gemm_kernel(
    const bf16_t* __restrict__ Abf, const bf16_t* __restrict__ Sbf,
    const bf16_t* __restrict__ Wst, const bf16_t* __restrict__ Wnt,
    const float* __restrict__ bias, float* __restrict__ out)
{
  __shared__ __align__(16) unsigned char pool[2 * SA_BYTES + 2 * SB_BYTES];

  const int tid = threadIdx.x;
  const int w = tid >> 6, l = tid & 63;
  const int kg = l >> 4, lr = l & 15;
  const int n0 = blockIdx.y * 64;              // block col base
  const int n0w = n0 + w * 16;                 // wave col base
  const int arow0 = blockIdx.x * 80;
  const int srow0 = blockIdx.x * 8;

  f32x4 acc[6] = {};

  // stage one 32-wide K slab: A 384 chunks (slots 0-5), B 512 chunks (6-13)
  auto STAGE = [&](int bsel, int k0) {
    bf16_t* aB = (bf16_t*)(pool + bsel * SA_BYTES);
    bf16_t* bB = (bf16_t*)(pool + 2 * SA_BYTES + bsel * SB_BYTES);
    #pragma unroll
    for (int r = 0; r < 4; ++r) {
      int slot = r * 4 + w;
      if (slot < 6) {
        int c = slot * 64 + l;
        int row = c >> 2, ch = c & 3;
        int sch = ch ^ ((row >> 1) & 3);
        const bf16_t* g = (slot < 5)
            ? Abf + (size_t)(arow0 + row) * D_DIM + k0 + sch * 8
            : Sbf + (size_t)(srow0 + (row & 7)) * D_DIM + k0 + sch * 8;
        gload_lds16(g, aB + (size_t)slot * 512);
      } else if (slot < 14) {
        int c = (slot - 6) * 64 + l;
        int mat = c >> 8, rc = c & 255;
        int row = rc >> 2, ch = rc & 3;
        int sch = ch ^ ((row >> 1) & 3);
        const bf16_t* W = mat ? Wnt : Wst;
        gload_lds16(W + (size_t)(n0 + row) * D_DIM + k0 + sch * 8,
                    bB + (size_t)(slot - 6) * 512);
      }
    }
  };

  STAGE(0, 0);
  __syncthreads();

  const int xorc = (kg ^ ((lr >> 1) & 3)) * 8;   // swizzled chunk -> elem off
  int cur = 0;
  #pragma unroll 2
  for (int t = 0; t < 16; ++t) {
    if (t < 15) STAGE(cur ^ 1, (t + 1) * 32);    // prefetch next slab

    const bf16_t* aC = (const bf16_t*)(pool + cur * SA_BYTES);
    const bf16_t* bC = (const bf16_t*)(pool + 2 * SA_BYTES + cur * SB_BYTES);
    bf16x8 af[6], bs, bn;
    #pragma unroll
    for (int s = 0; s < 6; ++s)
      af[s] = *(const bf16x8*)(aC + (s * 16 + lr) * 32 + xorc);
    bs = *(const bf16x8*)(bC + (w * 16 + lr) * 32 + xorc);
    bn = *(const bf16x8*)(bC + 2048 + (w * 16 + lr) * 32 + xorc);

    #pragma unroll
    for (int s = 0; s < 5; ++s)
      acc[s] = __builtin_amdgcn_mfma_f32_16x16x32_bf16(af[s], bs, acc[s], 0, 0, 0);
    acc[5] = __builtin_amdgcn_mfma_f32_16x16x32_bf16(af[5], bn, acc[5], 0, 0, 0);

    __syncthreads();   // drains prefetch vmcnt + fences LDS reads
    cur ^= 1;
  }

  // T tile -> per-wave LDS region (pool reuse; all staging reads fenced).
  // C/D layout: col = l&15, row = (l>>4)*4 + reg; strip-5 rows 8..15 dup 0..7.
  float* Tex = (float*)pool;                     // [4 waves][8][20]
  #pragma unroll
  for (int reg = 0; reg < 4; ++reg)
    Tex[(w * 8 + ((kg * 4 + reg) & 7)) * 20 + lr] = acc[5][reg];
  __syncthreads();

  const float bv = bias[n0w + lr];
  #pragma unroll
  for (int s = 0; s < 5; ++s) {
    #pragma unroll
    for (int reg = 0; reg < 4; ++reg) {
      int rloc = s * 16 + kg * 4 + reg;          // 0..79
      int ls = rloc / MAXREL;                    // local sample 0..7
      float v = acc[s][reg] + Tex[(w * 8 + ls) * 20 + lr] + bv;
      out[(size_t)(arow0 + rloc) * D_DIM + n0w + lr] = fmaxf(v, 0.0f);
    }
  }
}

extern "C" void kernel_launch(void* const* d_in, const int* in_sizes, int n_in,
                              void* d_out, int out_size, void* d_ws, size_t ws_size,
                              hipStream_t stream) {
  const float* x     = (const float*)d_in[0];   // [28672, 512]
  const float* Wself = (const float*)d_in[1];   // [512, 512]
  const float* Wnbr  = (const float*)d_in[2];   // [512, 512]
  const float* bias  = (const float*)d_in[3];   // [512]
  const int*   pairs = (const int*)d_in[5];     // [1024, 10, 2]

  char* ws = (char*)d_ws;
  size_t off = 0;
  bf16_t* Sbf = (bf16_t*)(ws + off); off += (size_t)B_SAMP * D_DIM * 2;
  bf16_t* Wst = (bf16_t*)(ws + off); off += (size_t)D_DIM * D_DIM * 2;
  bf16_t* Wnt = (bf16_t*)(ws + off); off += (size_t)D_DIM * D_DIM * 2;
  bf16_t* Abf = (bf16_t*)(ws + off); off += (size_t)OUTROWS * D_DIM * 2;

  prep_kernel<<<B_SAMP + 512, 256, 0, stream>>>(
      x, Wself, Wnbr, pairs, Sbf, Abf, Wst, Wnt);
  fused_gemm_kernel<<<dim3(OUTROWS / 80, D_DIM / 64), 256, 0, stream>>>(
      Abf, Sbf, Wst, Wnt, bias, (float*)d_out);
}